// Round 3
// baseline (276.084 us; speedup 1.0000x reference)
//
#include <hip/hip_runtime.h>
#include <math.h>

#define Bn 4
#define Nn 2048
#define Hn 8
#define HDn 32
#define Dn 256
#define MHALF 1024  // m-split: 2 partials merged in oproj

typedef _Float16 h1;
typedef __attribute__((ext_vector_type(8))) _Float16 h8;
typedef __attribute__((ext_vector_type(4))) float fx4;

#define QSCALE 0.35355339059327373f
// |S_raw| <= HD = 32, |S_raw*QSCALE*topo| <= 11.32 -> fixed softmax shift safe:
// p = e^{S-4} in [2.2e-7, 1503] -- fits f16, no running max needed.
#define SOFTMAX_SHIFT 4.0f

// ---------------------------------------------------------------------------
// Kernel 0: W -> f16 transpose via LDS tiles (coalesced both sides)
// ---------------------------------------------------------------------------
__global__ __launch_bounds__(256) void cvtW_kernel(
    const float* __restrict__ Wq, const float* __restrict__ Wk,
    const float* __restrict__ Wv, h1* __restrict__ WT)
{
    __shared__ float tw[64][65];
    const int w = blockIdx.z;
    const int d0 = blockIdx.y * 64, o0 = blockIdx.x * 64;
    const float* W = (w == 0) ? Wq : (w == 1) ? Wk : Wv;
    const int rr = threadIdx.x >> 6, cc = threadIdx.x & 63;
#pragma unroll
    for (int i = 0; i < 16; ++i)
        tw[rr + i * 4][cc] = W[(size_t)(d0 + rr + i * 4) * 256 + o0 + cc];
    __syncthreads();
#pragma unroll
    for (int i = 0; i < 16; ++i) {
        const int row = rr + i * 4;
        WT[(size_t)w * 65536 + (size_t)(o0 + row) * 256 + d0 + cc] = (h1)tw[cc][row];
    }
}

// ---------------------------------------------------------------------------
// Kernel 1: QKV projection via f16 MFMA (x split hi/lo for ~f32 accuracy).
// ---------------------------------------------------------------------------
__global__ __launch_bounds__(256) __attribute__((amdgpu_waves_per_eu(4, 4)))
void proj_kernel(
    const float* __restrict__ x, const h1* __restrict__ WT,
    const float* __restrict__ bq, const float* __restrict__ bk,
    const float* __restrict__ bv,
    h1* __restrict__ fq, h1* __restrict__ fk, h1* __restrict__ vT)
{
    __shared__ __align__(16) h1 fbuf[64][264];
    const int tid = threadIdx.x;
    const int w = tid >> 6;
    const int lane = tid & 63;
    const int quad = lane >> 4;
    const int l15 = lane & 15;
    const int wsel = blockIdx.y >> 1;
    const int hg = blockIdx.y & 1;
    const int r0 = blockIdx.x * 64;
    const int arow = r0 + w * 16 + l15;
    const int b = r0 >> 11, n0 = r0 & (Nn - 1);

    const h1* WTw = WT + (size_t)wsel * 65536;
    fx4 acc[8];
#pragma unroll
    for (int ct = 0; ct < 8; ++ct) acc[ct] = (fx4){0.f, 0.f, 0.f, 0.f};

    for (int ks = 0; ks < 8; ++ks) {
        float xv[8];
        *(float4*)&xv[0] = *(const float4*)&x[(size_t)arow * 256 + ks * 32 + quad * 8];
        *(float4*)&xv[4] = *(const float4*)&x[(size_t)arow * 256 + ks * 32 + quad * 8 + 4];
        h8 Ahi, Alo;
#pragma unroll
        for (int j = 0; j < 8; ++j) {
            const h1 hi = (h1)xv[j];
            Ahi[j] = hi;
            Alo[j] = (h1)(xv[j] - (float)hi);
        }
        h8 Bf[8];
#pragma unroll
        for (int ct = 0; ct < 8; ++ct)
            Bf[ct] = *(const h8*)&WTw[(size_t)(hg * 128 + ct * 16 + l15) * 256 + ks * 32 + quad * 8];
#pragma unroll
        for (int ct = 0; ct < 8; ++ct) {
            acc[ct] = __builtin_amdgcn_mfma_f32_16x16x32_f16(Ahi, Bf[ct], acc[ct], 0, 0, 0);
            acc[ct] = __builtin_amdgcn_mfma_f32_16x16x32_f16(Alo, Bf[ct], acc[ct], 0, 0, 0);
        }
    }

    const float* bias = (wsel == 0) ? bq : (wsel == 1) ? bk : bv;

    if (wsel < 2) {
        h1* f = (wsel == 0) ? fq : fk;
#pragma unroll
        for (int ct = 0; ct < 8; ++ct) {
            const int c = ct * 16 + l15;
            const float bb = bias[hg * 128 + c];
            const int hh4 = c >> 5, dd = c & 31;
#pragma unroll
            for (int r = 0; r < 4; ++r) {
                const float val = acc[ct][r] + bb;
                const float sv = __sinf(val), cv = __cosf(val);
                h1* fp = &fbuf[w * 16 + quad * 4 + r][hh4 * 64 + dd];
                fp[0]  = (h1)cv;
                fp[32] = (h1)sv;
            }
        }
        __syncthreads();
        const int row = tid >> 2, q4 = tid & 3;
#pragma unroll
        for (int g = 0; g < 8; ++g) {
            const int chunk = q4 + g * 4;
            const int hh4 = chunk >> 3, within = chunk & 7;
            const h8 val = *(const h8*)&fbuf[row][hh4 * 64 + within * 8];
            const int head = hg * 4 + hh4;
            *(h8*)&f[((size_t)(b * Hn + head) * Nn + n0 + row) * 64 + within * 8] = val;
        }
    } else {
        h1 (*vst)[132] = (h1(*)[132])fbuf;
#pragma unroll
        for (int ct = 0; ct < 8; ++ct) {
            const int c = ct * 16 + l15;
            const float bb = bias[hg * 128 + c];
#pragma unroll
            for (int r = 0; r < 4; ++r)
                vst[w * 16 + quad * 4 + r][c] = (h1)(acc[ct][r] + bb);
        }
        __syncthreads();
        const int c2 = tid & 127, half = tid >> 7;
        const int head = hg * 4 + (c2 >> 5), dd = c2 & 31;
        h1* vp = vT + ((size_t)((b * Hn + head) * HDn + dd)) * Nn + n0;
#pragma unroll
        for (int g = 0; g < 4; ++g) {
            const int gg = half * 4 + g;
            h8 pk;
#pragma unroll
            for (int j = 0; j < 8; ++j) pk[j] = vst[gg * 8 + j][c2];
            *(h8*)(vp + gg * 8) = pk;
        }
    }
}

// ---------------------------------------------------------------------------
// Kernel 2: fused attention. Block = 512 thr = 8 waves = ALL 8 heads of one
// (b, 32 q-rows, m-half) -> topo tile shared block-wide (67 MB HBM minimum).
//
// r8 post-mortem: occupancy was never the limit (2 blocks/CU grid cap).
// r9 post-mortem: K/V L2 latency is NOT on the critical path (reg-dbuf no
// gain); launch_bounds(512,4) let the allocator pin VGPR=64 and SPILL
// (WRITE_SIZE +4 MB scratch). Busy = Mfma 8.7 + VALU 24.7 = ~33% ->
// ~65% of each iteration is a fixed serial chain: barrier -> S-MFMA deps ->
// exp/VALU chain -> P LDS write -> lgkmcnt -> P read -> PV. Paid 32x.
//
// r10 CHANGE: pay the chain 16x instead of 32x. Each barrier PHASE now
// covers TWO independent 32-col m-subtiles (64 topo columns): one barrier +
// one lgkmcnt + one P-wait amortized over 2x MFMA/exp work, and subtile 1's
// S-MFMAs issue under subtile 0's exp chain (ILP across subtiles).
// amdgpu_waves_per_eu(4,4) replaces launch_bounds' min-waves arg so the
// allocator targets 4 waves/EU = 128 VGPR budget (kills the r9 spills).
// Topo prefetch widened to float4/thread. K/V loads issue at phase top
// (post-barrier; r9 proved prefetching them buys nothing).
// Fixed-shift softmax: no reductions in the loop.
// ---------------------------------------------------------------------------
__global__ __launch_bounds__(512) __attribute__((amdgpu_waves_per_eu(4, 4)))
void attn_kernel(
    const h1* __restrict__ fq, const h1* __restrict__ fk, const h1* __restrict__ vT,
    const float* __restrict__ topo, float* __restrict__ pacc, float* __restrict__ pl)
{
    __shared__ __align__(16) h1 Pw[8][32][72];   // 36.9 KB per-wave P (64 cols + pad)
    __shared__ __align__(16) float tbuf[2][32][68]; // 17.4 KB topo double buffer

    const int b = blockIdx.y;
    const int mh = blockIdx.z;
    const int n0 = blockIdx.x * 32;
    const int tid = threadIdx.x;
    const int w = tid >> 6;        // wave id = head
    const int h = w;
    const int lane = tid & 63;
    const int quad = lane >> 4;
    const int l15 = lane & 15;

    const h1* qfh = fq + (size_t)(b * Hn + h) * Nn * 64;
    const h1* kfh = fk + (size_t)(b * Hn + h) * Nn * 64;
    const h1* vTh = vT + (size_t)(b * Hn + h) * HDn * Nn;

    // topo cooperative-load mapping: thread -> (row, 4 cols); 32x64 f32 tile
    const int trow = tid >> 4, tcol4 = (tid & 15) * 4;
    const float* tpg = topo + (size_t)b * Nn * Nn + (size_t)(n0 + trow) * Nn + tcol4;

    h8 qfr[2][2];
#pragma unroll
    for (int qs = 0; qs < 2; ++qs)
#pragma unroll
        for (int ks = 0; ks < 2; ++ks)
            qfr[qs][ks] = *(const h8*)(qfh + (size_t)(n0 + qs * 16 + l15) * 64 + ks * 32 + quad * 8);

    fx4 acc[2][2];
    float lsum[2][4];
#pragma unroll
    for (int qs = 0; qs < 2; ++qs) {
#pragma unroll
        for (int ds = 0; ds < 2; ++ds) acc[qs][ds] = (fx4){0.f, 0.f, 0.f, 0.f};
#pragma unroll
        for (int r = 0; r < 4; ++r) lsum[qs][r] = 0.f;
    }

    const int mbase = mh * MHALF;
    const int NPH = MHALF / 64;          // 16 barrier phases
    const fx4 z4 = {0.f, 0.f, 0.f, 0.f};

    float4 rt = *(const float4*)(tpg + mbase);   // prefetch topo phase 0

    for (int ph = 0; ph < NPH; ++ph) {
        const int m0 = mbase + ph * 64;
        const int cur = ph & 1;

        // commit prefetched topo tile to LDS, issue next phase's topo load
        *(float4*)&tbuf[cur][trow][tcol4] = rt;
        if (ph < NPH - 1) rt = *(const float4*)(tpg + m0 + 64);
        // raw barrier: waits own LDS writes only; global prefetch stays in flight
        __asm__ volatile("s_waitcnt lgkmcnt(0)\n\ts_barrier" ::: "memory");

        // K/V fragments for both 32-col subtiles (per-head, L2-served)
        h8 kf[2][2][2];   // [sub][ms][ks]
        h8 vv[2][2];      // [sub][ds]
#pragma unroll
        for (int sub = 0; sub < 2; ++sub) {
            const int mm = m0 + sub * 32;
#pragma unroll
            for (int ms = 0; ms < 2; ++ms)
#pragma unroll
                for (int ks = 0; ks < 2; ++ks)
                    kf[sub][ms][ks] = *(const h8*)(kfh + (size_t)(mm + ms * 16 + l15) * 64 + ks * 32 + quad * 8);
#pragma unroll
            for (int ds = 0; ds < 2; ++ds)
                vv[sub][ds] = *(const h8*)(vTh + (size_t)(ds * 16 + l15) * Nn + mm + quad * 8);
        }

        // Per subtile: S = Qf @ Kf^T, then p = e^{S*topo*QSCALE - 4} -> Pw.
        // Subtiles are independent: sub1's MFMAs overlap sub0's exp chain.
#pragma unroll
        for (int sub = 0; sub < 2; ++sub) {
            fx4 S[2][2];
#pragma unroll
            for (int qs = 0; qs < 2; ++qs)
#pragma unroll
                for (int ms = 0; ms < 2; ++ms) {
                    fx4 tmp = __builtin_amdgcn_mfma_f32_16x16x32_f16(qfr[qs][0], kf[sub][ms][0], z4, 0, 0, 0);
                    S[qs][ms] = __builtin_amdgcn_mfma_f32_16x16x32_f16(qfr[qs][1], kf[sub][ms][1], tmp, 0, 0, 0);
                }
#pragma unroll
            for (int qs = 0; qs < 2; ++qs)
#pragma unroll
                for (int ms = 0; ms < 2; ++ms)
#pragma unroll
                    for (int r = 0; r < 4; ++r) {
                        const float tv = tbuf[cur][qs * 16 + quad * 4 + r][sub * 32 + ms * 16 + l15];
                        const float p = __expf(fmaf(S[qs][ms][r] * tv, QSCALE, -SOFTMAX_SHIFT));
                        lsum[qs][r] += p;
                        Pw[w][qs * 16 + quad * 4 + r][sub * 32 + ms * 16 + l15] = (h1)p;
                    }
        }
        __asm__ volatile("s_waitcnt lgkmcnt(0)" ::: "memory");

        // PV for both subtiles (Pw is per-wave: no barrier needed)
#pragma unroll
        for (int sub = 0; sub < 2; ++sub)
#pragma unroll
            for (int qs = 0; qs < 2; ++qs) {
                const h8 aP = *(const h8*)&Pw[w][qs * 16 + l15][sub * 32 + quad * 8];
#pragma unroll
                for (int ds = 0; ds < 2; ++ds)
                    acc[qs][ds] = __builtin_amdgcn_mfma_f32_16x16x32_f16(aP, vv[sub][ds], acc[qs][ds], 0, 0, 0);
            }
    }

    // epilogue: reduce l across the 16 col-lanes, write partials
#pragma unroll
    for (int qs = 0; qs < 2; ++qs)
#pragma unroll
        for (int r = 0; r < 4; ++r)
#pragma unroll
            for (int off = 1; off <= 8; off <<= 1)
                lsum[qs][r] += __shfl_xor(lsum[qs][r], off);

    float* paccm = pacc + (size_t)mh * Bn * Nn * Dn;
    float* plm   = pl   + (size_t)mh * Bn * Nn * Hn;
#pragma unroll
    for (int qs = 0; qs < 2; ++qs)
#pragma unroll
        for (int r = 0; r < 4; ++r) {
            const size_t grow = (size_t)b * Nn + n0 + qs * 16 + quad * 4 + r;
            paccm[grow * Dn + h * HDn + l15]      = acc[qs][0][r];
            paccm[grow * Dn + h * HDn + 16 + l15] = acc[qs][1][r];
            if (l15 == 0) plm[grow * Hn + h] = lsum[qs][r];
        }
}

// ---------------------------------------------------------------------------
// Kernel 3: merge 2 partials + output projection. 8 rows/block, thread=col.
// ---------------------------------------------------------------------------
__global__ __launch_bounds__(256) void oproj_kernel(
    const float* __restrict__ pacc, const float* __restrict__ pl,
    const float* __restrict__ Wo, const float* __restrict__ bo,
    float* __restrict__ out)
{
    __shared__ float ysT[256][12];
    const int t = threadIdx.x;
    const int r0 = blockIdx.x * 8;
    const int h = t >> 5;
    const size_t PACC = (size_t)Bn * Nn * Dn;
    const size_t PL = (size_t)Bn * Nn * Hn;
#pragma unroll
    for (int i = 0; i < 8; ++i) {
        const size_t row = (size_t)(r0 + i);
        float l = 0.f, yv = 0.f;
#pragma unroll
        for (int m = 0; m < 2; ++m) {
            l  += pl[m * PL + row * Hn + h];
            yv += pacc[m * PACC + row * Dn + t];
        }
        ysT[t][i] = yv * __builtin_amdgcn_rcpf(l);
    }
    __syncthreads();

    float acc8[8];
#pragma unroll
    for (int i = 0; i < 8; ++i) acc8[i] = 0.f;
#pragma unroll 4
    for (int d = 0; d < 256; ++d) {
        const float wv = Wo[d * 256 + t];
        float yy[8];
        *(float4*)&yy[0] = *(const float4*)&ysT[d][0];
        *(float4*)&yy[4] = *(const float4*)&ysT[d][4];
#pragma unroll
        for (int i = 0; i < 8; ++i) acc8[i] = fmaf(yy[i], wv, acc8[i]);
    }
    const float bb = bo[t];
#pragma unroll
    for (int i = 0; i < 8; ++i)
        out[(size_t)(r0 + i) * 256 + t] = acc8[i] + bb;
}

// ---------------------------------------------------------------------------
extern "C" void kernel_launch(void* const* d_in, const int* in_sizes, int n_in,
                              void* d_out, int out_size, void* d_ws, size_t ws_size,
                              hipStream_t stream)
{
    const float* x    = (const float*)d_in[0];
    const float* topo = (const float*)d_in[1];
    const float* Wq   = (const float*)d_in[2];
    const float* bq   = (const float*)d_in[3];
    const float* Wk   = (const float*)d_in[4];
    const float* bk   = (const float*)d_in[5];
    const float* Wv   = (const float*)d_in[6];
    const float* bv   = (const float*)d_in[7];
    const float* Wo   = (const float*)d_in[8];
    const float* bo   = (const float*)d_in[9];
    float* out = (float*)d_out;

    char* ws = (char*)d_ws;
    const size_t MB = 1024 * 1024;
    h1* WT = (h1*)ws;
    h1* fq = (h1*)(ws + 1 * MB);
    h1* fk = (h1*)(ws + 9 * MB);
    h1* vT = (h1*)(ws + 17 * MB);
    float* pacc = (float*)(ws + 21 * MB);
    float* pl   = (float*)(ws + 37 * MB);

    cvtW_kernel<<<dim3(4, 4, 3), 256, 0, stream>>>(Wq, Wk, Wv, WT);
    proj_kernel<<<dim3(128, 6), 256, 0, stream>>>(x, WT, bq, bk, bv, fq, fk, vT);
    attn_kernel<<<dim3(Nn / 32, Bn, 2), 512, 0, stream>>>(fq, fk, vT, topo, pacc, pl);
    oproj_kernel<<<(Bn * Nn) / 8, 256, 0, stream>>>(pacc, pl, Wo, bo, out);
}